// Round 3
// baseline (2582.125 us; speedup 1.0000x reference)
//
#include <hip/hip_runtime.h>
#include <math.h>

#define EMBED 128

// ---------------------------------------------------------------------------
// pairs dtype detector: reference declares int64 but harness may hand int32.
// int64 little-endian: every odd 32-bit slot is a high word of a value
// < 100000 -> zero. int32: odd slots are random t indices. One wave checks
// the first 512 odd slots; flag=1 means int32 layout.
// ---------------------------------------------------------------------------
__global__ void detect_kernel(const unsigned int* __restrict__ pairs,
                              int* __restrict__ flag) {
    unsigned v = 0;
    int lane = threadIdx.x;  // 64 lanes
#pragma unroll
    for (int i = 0; i < 8; ++i) {
        v |= pairs[2 * (lane * 8 + i) + 1];
    }
    unsigned long long b = __ballot(v != 0);
    if (lane == 0) *flag = (b != 0ULL) ? 1 : 0;
}

// ---------------------------------------------------------------------------
// Node precompute: p in [0, 2*n_nodes). node=p>>1, which=p&1.
// which==0: tab row = b1 + h[node] @ W1[0:128]      (A table, b1 folded in)
// which==1: tab row =      h[node] @ W1[128:256]    (B table)
// ---------------------------------------------------------------------------
__global__ __launch_bounds__(256) void node_pre_kernel(
    const float* __restrict__ h, const float* __restrict__ W1,
    const float* __restrict__ b1, float* __restrict__ tab, int n2)
{
    int p = blockIdx.x * 256 + threadIdx.x;
    if (p >= n2) return;
    int node = p >> 1;
    int which = p & 1;
    const float4* __restrict__ hv = (const float4*)(h + (size_t)node * EMBED);
    const float* __restrict__ W = W1 + (size_t)which * 128 * 128;

    float acc[128];
    if (which == 0) {
#pragma unroll
        for (int j = 0; j < 128; ++j) acc[j] = b1[j];
    } else {
#pragma unroll
        for (int j = 0; j < 128; ++j) acc[j] = 0.0f;
    }

#pragma unroll 1
    for (int d4 = 0; d4 < EMBED / 4; ++d4) {
        float4 a = hv[d4];
        float av[4] = {a.x, a.y, a.z, a.w};
#pragma unroll
        for (int dd = 0; dd < 4; ++dd) {
            const float* __restrict__ w = W + (size_t)(d4 * 4 + dd) * 128;
            float f = av[dd];
#pragma unroll
            for (int j = 0; j < 128; ++j) acc[j] = fmaf(f, w[j], acc[j]);
        }
    }

    float4* __restrict__ o = (float4*)(tab + (size_t)p * 128);
#pragma unroll
    for (int j4 = 0; j4 < 32; ++j4)
        o[j4] = make_float4(acc[4 * j4], acc[4 * j4 + 1],
                            acc[4 * j4 + 2], acc[4 * j4 + 3]);
}

// ---------------------------------------------------------------------------
// Factored pair kernel: acc = A[s] + B[t]; then only the pair-dependent
// feature blocks (hs*ht)@W1c + |hs-ht|@W1d; then layers 2/3 unrolled.
// ---------------------------------------------------------------------------
__global__ __launch_bounds__(256) void pair_kernel_f(
    const float* __restrict__ h,
    const int* __restrict__ pairs,
    const int* __restrict__ flag,
    const float* __restrict__ tab,
    const float* __restrict__ W1,
    const float* __restrict__ W2, const float* __restrict__ b2,
    const float* __restrict__ W3, const float* __restrict__ b3,
    float* __restrict__ out, int npairs)
{
    int p = blockIdx.x * 256 + threadIdx.x;
    if (p >= npairs) return;

    int s, t;
    if (*flag == 0) {   // int64 layout: low words at 4p, 4p+2
        s = pairs[4 * p];
        t = pairs[4 * p + 2];
    } else {            // int32 layout
        s = pairs[2 * p];
        t = pairs[2 * p + 1];
    }

    const float4* __restrict__ As = (const float4*)(tab + (size_t)(2 * s) * 128);
    const float4* __restrict__ Bt = (const float4*)(tab + (size_t)(2 * t + 1) * 128);

    float acc[128];
#pragma unroll
    for (int j4 = 0; j4 < 32; ++j4) {
        float4 a = As[j4];
        float4 b = Bt[j4];
        acc[4 * j4 + 0] = a.x + b.x;
        acc[4 * j4 + 1] = a.y + b.y;
        acc[4 * j4 + 2] = a.z + b.z;
        acc[4 * j4 + 3] = a.w + b.w;
    }

    const float4* __restrict__ hs4 = (const float4*)(h + (size_t)s * EMBED);
    const float4* __restrict__ ht4 = (const float4*)(h + (size_t)t * EMBED);
    const float* __restrict__ Wc = W1 + (size_t)256 * 128;
    const float* __restrict__ Wd = W1 + (size_t)384 * 128;

#pragma unroll 1
    for (int d4 = 0; d4 < EMBED / 4; ++d4) {
        float4 a = hs4[d4];
        float4 b = ht4[d4];
        float av[4] = {a.x, a.y, a.z, a.w};
        float bv[4] = {b.x, b.y, b.z, b.w};
#pragma unroll
        for (int dd = 0; dd < 4; ++dd) {
            int k = d4 * 4 + dd;
            float f2 = av[dd] * bv[dd];
            float f3 = fabsf(av[dd] - bv[dd]);
            const float* __restrict__ wc = Wc + (size_t)k * 128;
            const float* __restrict__ wd = Wd + (size_t)k * 128;
#pragma unroll
            for (int j = 0; j < 128; ++j) {
                float v = acc[j];
                v = fmaf(f2, wc[j], v);
                v = fmaf(f3, wd[j], v);
                acc[j] = v;
            }
        }
    }

#pragma unroll
    for (int j = 0; j < 128; ++j) acc[j] = fmaxf(acc[j], 0.0f);

    // ---- layer 2: x1[128] @ W2[128][64] + b2 ----
    float x2[64];
#pragma unroll
    for (int j = 0; j < 64; ++j) x2[j] = b2[j];
#pragma unroll
    for (int k = 0; k < 128; ++k) {
        float xv = acc[k];
#pragma unroll
        for (int j = 0; j < 64; ++j)
            x2[j] = fmaf(xv, W2[(size_t)k * 64 + j], x2[j]);
    }

    // ---- layer 3: relu(x2)[64] @ W3[64] + b3 ----
    float lg = b3[0];
#pragma unroll
    for (int k = 0; k < 64; ++k)
        lg = fmaf(fmaxf(x2[k], 0.0f), W3[k], lg);

    out[p] = lg;
}

// ---------------------------------------------------------------------------
// Fallback: direct (unfactored) per-pair kernel, used if d_ws can't hold
// the 2*n_nodes*128 fp32 node tables.
// ---------------------------------------------------------------------------
__global__ __launch_bounds__(256) void mlp_kernel(
    const float* __restrict__ h,
    const int* __restrict__ pairs,
    const int* __restrict__ flag,
    const float* __restrict__ W1, const float* __restrict__ b1,
    const float* __restrict__ W2, const float* __restrict__ b2,
    const float* __restrict__ W3, const float* __restrict__ b3,
    float* __restrict__ out, int npairs)
{
    int p = blockIdx.x * 256 + threadIdx.x;
    if (p >= npairs) return;

    int s, t;
    if (*flag == 0) {
        s = pairs[4 * p];
        t = pairs[4 * p + 2];
    } else {
        s = pairs[2 * p];
        t = pairs[2 * p + 1];
    }

    const float4* __restrict__ hs4 = (const float4*)(h + (size_t)s * EMBED);
    const float4* __restrict__ ht4 = (const float4*)(h + (size_t)t * EMBED);

    float acc[128];
#pragma unroll
    for (int j = 0; j < 128; ++j) acc[j] = b1[j];

#pragma unroll 1
    for (int d4 = 0; d4 < EMBED / 4; ++d4) {
        float4 a = hs4[d4];
        float4 b = ht4[d4];
        float av[4] = {a.x, a.y, a.z, a.w};
        float bv[4] = {b.x, b.y, b.z, b.w};
#pragma unroll
        for (int dd = 0; dd < 4; ++dd) {
            int k = d4 * 4 + dd;
            float f0 = av[dd];
            float f1 = bv[dd];
            float f2 = f0 * f1;
            float f3 = fabsf(f0 - f1);
            const float* __restrict__ w0 = W1 + (size_t)k * 128;
            const float* __restrict__ w1r = w0 + 128 * 128;
            const float* __restrict__ w2r = w0 + 256 * 128;
            const float* __restrict__ w3r = w0 + 384 * 128;
#pragma unroll
            for (int j = 0; j < 128; ++j) {
                float v0 = acc[j];
                v0 = fmaf(f0, w0[j], v0);
                v0 = fmaf(f1, w1r[j], v0);
                v0 = fmaf(f2, w2r[j], v0);
                v0 = fmaf(f3, w3r[j], v0);
                acc[j] = v0;
            }
        }
    }

#pragma unroll
    for (int j = 0; j < 128; ++j) acc[j] = fmaxf(acc[j], 0.0f);

    float x2[64];
#pragma unroll
    for (int j = 0; j < 64; ++j) x2[j] = b2[j];
#pragma unroll
    for (int k = 0; k < 128; ++k) {
        float xv = acc[k];
#pragma unroll
        for (int j = 0; j < 64; ++j)
            x2[j] = fmaf(xv, W2[(size_t)k * 64 + j], x2[j]);
    }

    float lg = b3[0];
#pragma unroll
    for (int k = 0; k < 64; ++k)
        lg = fmaf(fmaxf(x2[k], 0.0f), W3[k], lg);

    out[p] = lg;
}

extern "C" void kernel_launch(void* const* d_in, const int* in_sizes, int n_in,
                              void* d_out, int out_size, void* d_ws, size_t ws_size,
                              hipStream_t stream) {
    const float* h   = (const float*)d_in[0];
    const int* pairs = (const int*)d_in[1];
    const float* W1  = (const float*)d_in[2];
    const float* b1  = (const float*)d_in[3];
    const float* W2  = (const float*)d_in[4];
    const float* b2  = (const float*)d_in[5];
    const float* W3  = (const float*)d_in[6];
    const float* b3  = (const float*)d_in[7];
    float* out = (float*)d_out;

    int npairs  = out_size;               // one logit per pair
    int n_nodes = in_sizes[0] / EMBED;

    int*   flag = (int*)d_ws;
    float* tab  = (float*)((char*)d_ws + 16);   // keep 16B alignment for float4
    size_t need = 16 + (size_t)n_nodes * 2 * EMBED * sizeof(float);

    detect_kernel<<<1, 64, 0, stream>>>((const unsigned int*)pairs, flag);

    if (ws_size >= need) {
        int n2 = 2 * n_nodes;
        node_pre_kernel<<<(n2 + 255) / 256, 256, 0, stream>>>(h, W1, b1, tab, n2);
        pair_kernel_f<<<(npairs + 255) / 256, 256, 0, stream>>>(
            h, pairs, flag, tab, W1, W2, b2, W3, b3, out, npairs);
    } else {
        mlp_kernel<<<(npairs + 255) / 256, 256, 0, stream>>>(
            h, pairs, flag, W1, b1, W2, b2, W3, b3, out, npairs);
    }
}